// Round 9
// baseline (489.839 us; speedup 1.0000x reference)
//
#include <hip/hip_runtime.h>
#include <hip/hip_fp16.h>

#define B_ 64
#define L_ 128
#define E_ 300
#define HD_ 200
#define H_ 400
#define S_ 50
#define START_ 48
#define END_ 49
#define NG_ 1600
#define BL_ 8192

// ---- ws layout (bytes) ----
#define OFF_XG   0ull                         // bf16 [8192][1600]  26,214,400
#define OFF_LSTM (OFF_XG + 26214400ull)       // f32  [8192][400]   13,107,200
#define OFF_SH   (OFF_LSTM + 13107200ull)     // max(w16q 640,000 ; feats 1,638,400)
#define OFF_WTT  (OFF_SH + 1638400ull)        // f32  [400][50]     80,000
#define OFF_ACC  (OFF_WTT + 80000ull)         // f32  [1]

typedef __attribute__((ext_vector_type(8))) short short8;
typedef __attribute__((ext_vector_type(4))) float f32x4;
typedef _Float16 h2v __attribute__((ext_vector_type(2)));

__device__ __forceinline__ unsigned short f32_to_bf16(float f) {
    unsigned u = __float_as_uint(f);
    unsigned r = u + 0x7fffu + ((u >> 16) & 1u);
    return (unsigned short)(r >> 16);
}
__device__ __forceinline__ float bf16_to_f32(unsigned short s) {
    return __uint_as_float(((unsigned)s) << 16);
}
__device__ __forceinline__ unsigned packh2(float a, float b) {
    return (unsigned)__half_as_ushort(__float2half(a)) |
           ((unsigned)__half_as_ushort(__float2half(b)) << 16);
}
__device__ __forceinline__ float hlo(unsigned u) {
    return __half2float(__ushort_as_half((unsigned short)(u & 0xffffu)));
}
__device__ __forceinline__ float hhi(unsigned u) {
    return __half2float(__ushort_as_half((unsigned short)(u >> 16)));
}
// 2-wide f16 dot with f32 accumulate: v_dot2_f32_f16 (fallback: cvt+fma).
__device__ __forceinline__ float fdot2(unsigned w, unsigned h, float c) {
#if __has_builtin(__builtin_amdgcn_fdot2)
    return __builtin_amdgcn_fdot2(__builtin_bit_cast(h2v, w), __builtin_bit_cast(h2v, h), c, false);
#else
    c = fmaf(hlo(w), hlo(h), c);
    return fmaf(hhi(w), hhi(h), c);
#endif
}

// ---------------- prep: w_hh (both dirs) -> f16x2 uint4 [dir][kq(25)][row(800)];
// W_tag transpose; acc=0.  word(kq,row) packs w[row][8kq..8kq+7]. (unchanged)
__global__ void prep_kernel(const float* __restrict__ whh_f, const float* __restrict__ whh_b,
                            const float* __restrict__ wtag, float* __restrict__ wtagT,
                            uint4* __restrict__ w16q, float* __restrict__ acc) {
    int g = blockIdx.x * 256 + threadIdx.x;
    if (g < 40000) {
        int dir = g / 20000;
        int r = g % 20000;
        int kq = r / 800;
        int row = r % 800;
        const float* w = dir ? whh_b : whh_f;
        const float* src = w + row * HD_ + 8 * kq;
        uint4 o;
        o.x = packh2(src[0], src[1]);
        o.y = packh2(src[2], src[3]);
        o.z = packh2(src[4], src[5]);
        o.w = packh2(src[6], src[7]);
        w16q[g] = o;
    }
    if (g < 20000) {
        int k = g / S_, s = g % S_;
        wtagT[g] = wtag[s * H_ + k];
    }
    if (g == 0) acc[0] = 0.f;
}

// ---------------- xg GEMM (MFMA bf16): unchanged.
__global__ __launch_bounds__(256) void xg_gemm(const int* __restrict__ words,
                                               const float* __restrict__ emb,
                                               const float* __restrict__ wihf,
                                               const float* __restrict__ wihb,
                                               const float* __restrict__ bfc,
                                               const float* __restrict__ bbc,
                                               unsigned short* __restrict__ xg) {
    __shared__ unsigned short As[128 * 40];
    __shared__ unsigned short Bs[128 * 40];
    __shared__ int wlds[128];
    int tid = threadIdx.x;
    int bm = blockIdx.y * 128;
    int bn = blockIdx.x * 128;
    if (tid < 128) wlds[tid] = words[bm + tid];
    __syncthreads();

    int srow = tid >> 1;
    int ks = (tid & 1) * 16;
    int lane = tid & 63;
    int wave = tid >> 6;
    int r16 = lane & 15;
    int kh = lane >> 4;

    f32x4 acc[2][8];
#pragma unroll
    for (int mi = 0; mi < 2; ++mi)
#pragma unroll
        for (int ni = 0; ni < 8; ++ni) acc[mi][ni] = (f32x4){0.f, 0.f, 0.f, 0.f};

    const float* arow = emb + (long)wlds[srow] * E_;
    int gB = bn + srow;
    const float* brow = (gB < 800) ? (wihf + (long)gB * E_) : (wihb + (long)(gB - 800) * E_);
    bool bvalid = gB < NG_;

    for (int k0 = 0; k0 < 320; k0 += 32) {
#pragma unroll
        for (int j = 0; j < 4; ++j) {
            int k = k0 + ks + 4 * j;
            float4 va = (k < E_) ? *(const float4*)(arow + k) : make_float4(0.f, 0.f, 0.f, 0.f);
            unsigned p0 = (unsigned)f32_to_bf16(va.x) | ((unsigned)f32_to_bf16(va.y) << 16);
            unsigned p1 = (unsigned)f32_to_bf16(va.z) | ((unsigned)f32_to_bf16(va.w) << 16);
            *(uint2*)&As[srow * 40 + ks + 4 * j] = make_uint2(p0, p1);
            float4 vb = (bvalid && k < E_) ? *(const float4*)(brow + k) : make_float4(0.f, 0.f, 0.f, 0.f);
            unsigned q0 = (unsigned)f32_to_bf16(vb.x) | ((unsigned)f32_to_bf16(vb.y) << 16);
            unsigned q1 = (unsigned)f32_to_bf16(vb.z) | ((unsigned)f32_to_bf16(vb.w) << 16);
            *(uint2*)&Bs[srow * 40 + ks + 4 * j] = make_uint2(q0, q1);
        }
        __syncthreads();
        short8 af[2], bfv[8];
#pragma unroll
        for (int mi = 0; mi < 2; ++mi)
            af[mi] = *(const short8*)&As[(wave * 32 + mi * 16 + r16) * 40 + kh * 8];
#pragma unroll
        for (int ni = 0; ni < 8; ++ni)
            bfv[ni] = *(const short8*)&Bs[(ni * 16 + r16) * 40 + kh * 8];
#pragma unroll
        for (int mi = 0; mi < 2; ++mi)
#pragma unroll
            for (int ni = 0; ni < 8; ++ni)
                acc[mi][ni] = __builtin_amdgcn_mfma_f32_16x16x32_bf16(af[mi], bfv[ni], acc[mi][ni], 0, 0, 0);
        __syncthreads();
    }
#pragma unroll
    for (int ni = 0; ni < 8; ++ni) {
        int g = bn + ni * 16 + r16;
        if (g < NG_) {
            float bias = (g < 800) ? bfc[g] : bbc[g - 800];
#pragma unroll
            for (int mi = 0; mi < 2; ++mi) {
#pragma unroll
                for (int r = 0; r < 4; ++r) {
                    int row = bm + wave * 32 + mi * 16 + kh * 4 + r;
                    xg[(long)row * NG_ + g] = f32_to_bf16(acc[mi][ni][r] + bias);
                }
            }
        }
    }
}

// ---------------- LSTM recurrence: block=(dir,b), 512 thr (8 waves).
// Allocator model (R3-R8): VGPR cap = f(thread count only), 512thr -> cap 128; attributes
// and LDS size are IGNORED by the cap heuristic. Full register residency impossible
// (320KB weights > any block's reg capacity). HYBRID:
//   threads 0..399: reg-row `tid` (gates i/f) = 25 uint4 = 100 VGPR (pressure ~125 <= 128)
//                 + LDS-row `tid+400` (gates g/o) streamed from a 160,000 B LDS copy.
// LDS weight layout [kq(25)][row'(400)] uint4 -> lanes read consecutive 16B -> conflict-free.
// LDS = 160,000 (w) + 400 (h16) + 3,200 (a_lds) = 163,600 <= 163,840.
__global__ __launch_bounds__(512) void lstm_rec(const unsigned short* __restrict__ xg,
                                                const uint4* __restrict__ w16q,
                                                float* __restrict__ lstm_out) {
    __shared__ __align__(16) unsigned char lds_raw[163600];
    uint4* wl4 = (uint4*)lds_raw;                               // [25][400] uint4
    unsigned short* h16 = (unsigned short*)(lds_raw + 160000);  // packed f16 h, 400 B
    float* a_lds = (float*)(lds_raw + 160400);                  // gates [q*200+ko], 3200 B
    int tid = threadIdx.x;
    int dir = blockIdx.x >> 6;
    int b = blockIdx.x & 63;
    bool act = tid < 400;
    int tw = act ? tid : 0;

    const uint4* wp = w16q + dir * 20000;
    // Stage LDS half (rows 400..799) once: [kq][row'] identical sub-layout of w16q.
    for (int i = tid; i < 10000; i += 512) {
        int kq = i / 400, r = i - kq * 400;
        wl4[i] = wp[kq * 800 + 400 + r];
    }
    // Register half (rows 0..399 = gates i,f), pinned against remat.
    uint4 wA[25];
#pragma unroll
    for (int kq = 0; kq < 25; ++kq) wA[kq] = wp[kq * 800 + tw];
#pragma unroll
    for (int kq = 0; kq < 25; ++kq)
        asm volatile("" : "+v"(wA[kq].x), "+v"(wA[kq].y), "+v"(wA[kq].z), "+v"(wA[kq].w));

    if (tid < HD_) h16[tid] = 0;
    float c = 0.f;
    __syncthreads();
    const uint4* h4 = (const uint4*)h16;
    const unsigned short* xbase = xg + (long)b * L_ * NG_ + dir * 800;

    int t0 = dir ? (L_ - 1) : 0;
    float xr = act ? bf16_to_f32(xbase[(long)t0 * NG_ + tid]) : 0.f;         // i/f input
    float xl = act ? bf16_to_f32(xbase[(long)t0 * NG_ + tid + 400]) : 0.f;   // g/o input

    for (int step = 0; step < L_; ++step) {
        int t = dir ? (L_ - 1 - step) : step;
        float xr_n = 0.f, xl_n = 0.f;
        if (act && step + 1 < L_) {
            int tn = dir ? (t - 1) : (t + 1);
            xr_n = bf16_to_f32(xbase[(long)tn * NG_ + tid]);
            xl_n = bf16_to_f32(xbase[(long)tn * NG_ + tid + 400]);
        }
        if (act) {
            float s0 = xr, s1 = 0.f;     // reg-row (i or f)
            float u0 = xl, u1 = 0.f;     // lds-row (g or o)
#pragma unroll
            for (int kq = 0; kq < 25; ++kq) {
                uint4 hv = h4[kq];
                uint4 wl = wl4[kq * 400 + tid];
                uint4 a = wA[kq];
                s0 = fdot2(a.x, hv.x, s0); s1 = fdot2(a.y, hv.y, s1);
                s0 = fdot2(a.z, hv.z, s0); s1 = fdot2(a.w, hv.w, s1);
                u0 = fdot2(wl.x, hv.x, u0); u1 = fdot2(wl.y, hv.y, u1);
                u0 = fdot2(wl.z, hv.z, u0); u1 = fdot2(wl.w, hv.w, u1);
            }
            float pr = s0 + s1;          // i (tid<200) / f preact
            float pl = u0 + u1;          // g (tid<200) / o preact
            a_lds[tid] = 1.f / (1.f + __expf(-pr));              // sig(i) / sig(f)
            if (tid < 200) {
                float e = __expf(-2.f * pl);                     // tanh(g)
                a_lds[400 + tid] = 2.f / (1.f + e) - 1.f;
            } else {
                a_lds[400 + tid] = 1.f / (1.f + __expf(-pl));    // sig(o)
            }
        }
        __syncthreads();
        if (tid < HD_) {
            float ig = a_lds[tid];
            float fg = a_lds[200 + tid];
            float gg = a_lds[400 + tid];
            float og = a_lds[600 + tid];
            c = fg * c + ig * gg;
            float ec = __expf(-2.f * c);
            float hn = og * (2.f / (1.f + ec) - 1.f);
            h16[tid] = (unsigned short)__half_as_ushort(__float2half(hn));
            lstm_out[((long)(b * L_ + t)) * H_ + dir * HD_ + tid] = hn;
        }
        xr = xr_n; xl = xl_n;
        __syncthreads();
    }
}

// ---------------- features = lstm_out @ W_tag^T + b_tag
__global__ __launch_bounds__(256) void feat_kernel(const float* __restrict__ lstm_out,
                                                   const float* __restrict__ wtagT,
                                                   const float* __restrict__ btag,
                                                   float* __restrict__ feats) {
    __shared__ float hrow[4 * H_];
    int tid = threadIdx.x;
    int base = blockIdx.x * 4;
    for (int idx = tid; idx < 4 * H_; idx += 256)
        hrow[idx] = lstm_out[(long)base * H_ + idx];
    __syncthreads();
    int il = tid >> 6, s = tid & 63;
    if (s < S_) {
        float acc = btag[s];
        const float* hr = hrow + il * H_;
#pragma unroll 4
        for (int k = 0; k < H_; ++k)
            acc = fmaf(hr[k], wtagT[k * S_ + s], acc);
        feats[(base + il) * S_ + s] = acc;
    }
}

// ---------------- CRF forward + labeled score. Block=batch, 512 thr: j=tid>>3, 8 lanes/j.
__global__ __launch_bounds__(512) void crf_kernel(const float* __restrict__ feats,
                                                  const float* __restrict__ trans,
                                                  const int* __restrict__ tags,
                                                  const int* __restrict__ seqlens,
                                                  float* __restrict__ acc) {
    __shared__ float Tt[S_ * S_];   // Tt[j*50+i] = trans[i*50+j]
    __shared__ float alpha[S_];
    __shared__ float lastal[S_];
    __shared__ int tg[L_];
    int tid = threadIdx.x;
    int b = blockIdx.x;
    for (int idx = tid; idx < S_ * S_; idx += 512) {
        int j = idx / S_, i = idx % S_;
        Tt[idx] = trans[i * S_ + j];
    }
    if (tid < L_) tg[tid] = tags[b * L_ + tid];
    int slen = seqlens[b];
    const float* fb = feats + (long)b * L_ * S_;
    __syncthreads();
    if (tid < S_) {
        float a = Tt[tid * S_ + START_] + fb[tid];
        alpha[tid] = a;
        if (slen == 1) lastal[tid] = a;
    }
    __syncthreads();
    int j = tid >> 3, sub = tid & 7;
    bool jact = j < S_;
    for (int t = 1; t < L_; ++t) {
        float anew = 0.f;
        if (jact) {
            float m = -1e30f;
            for (int i = sub; i < S_; i += 8) m = fmaxf(m, alpha[i] + Tt[j * S_ + i]);
            m = fmaxf(m, __shfl_xor(m, 1));
            m = fmaxf(m, __shfl_xor(m, 2));
            m = fmaxf(m, __shfl_xor(m, 4));
            float s = 0.f;
            for (int i = sub; i < S_; i += 8) s += __expf(alpha[i] + Tt[j * S_ + i] - m);
            s += __shfl_xor(s, 1);
            s += __shfl_xor(s, 2);
            s += __shfl_xor(s, 4);
            anew = m + __logf(s) + fb[t * S_ + j];
        }
        __syncthreads();
        if (jact && sub == 0) {
            alpha[j] = anew;
            if (t == slen - 1) lastal[j] = anew;
        }
        __syncthreads();
    }
    if (tid < 64) {
        float la = (tid < S_) ? (lastal[tid] + Tt[END_ * S_ + tid]) : -1e30f;
        float m = la;
        for (int off = 32; off; off >>= 1) m = fmaxf(m, __shfl_xor(m, off));
        float e = (tid < S_) ? __expf(la - m) : 0.f;
        for (int off = 32; off; off >>= 1) e += __shfl_xor(e, off);
        float unl = m + __logf(e);
        float lab = 0.f;
        for (int tt = tid; tt < L_; tt += 64) {
            if (tt == 0) {
                lab += Tt[tg[0] * S_ + START_] + fb[tg[0]];
            } else if (tt < slen) {
                lab += Tt[tg[tt] * S_ + tg[tt - 1]] + fb[tt * S_ + tg[tt]];
            }
        }
        if (tid == 0) lab += Tt[END_ * S_ + tg[slen - 1]];
        for (int off = 32; off; off >>= 1) lab += __shfl_xor(lab, off);
        if (tid == 0) atomicAdd(acc, unl - lab);
    }
}

__global__ void fin_kernel(const float* __restrict__ acc, float* __restrict__ out) {
    out[0] = acc[0];
}

extern "C" void kernel_launch(void* const* d_in, const int* in_sizes, int n_in,
                              void* d_out, int out_size, void* d_ws, size_t ws_size,
                              hipStream_t stream) {
    const int*   words = (const int*)d_in[0];
    const int*   slens = (const int*)d_in[1];
    // d_in[2] = masks: semantically (t < seq_len); not read.
    const int*   tags  = (const int*)d_in[3];
    const float* emb   = (const float*)d_in[4];
    const float* wihf  = (const float*)d_in[5];
    const float* whhf  = (const float*)d_in[6];
    const float* bf    = (const float*)d_in[7];
    const float* wihb  = (const float*)d_in[8];
    const float* whhb  = (const float*)d_in[9];
    const float* bb    = (const float*)d_in[10];
    const float* wtag  = (const float*)d_in[11];
    const float* btag  = (const float*)d_in[12];
    const float* trans = (const float*)d_in[13];

    char* ws = (char*)d_ws;
    unsigned short* xg   = (unsigned short*)(ws + OFF_XG);
    float*          lstm = (float*)(ws + OFF_LSTM);
    uint4*          w16q = (uint4*)(ws + OFF_SH);   // prep -> lstm
    float*          fts  = (float*)(ws + OFF_SH);   // feat -> crf (time-shared)
    float*          wtT  = (float*)(ws + OFF_WTT);
    float*          accb = (float*)(ws + OFF_ACC);
    float*          out  = (float*)d_out;

    prep_kernel<<<157, 256, 0, stream>>>(whhf, whhb, wtag, wtT, w16q, accb);
    xg_gemm<<<dim3(13, 64), 256, 0, stream>>>(words, emb, wihf, wihb, bf, bb, xg);
    lstm_rec<<<128, 512, 0, stream>>>(xg, w16q, lstm);
    feat_kernel<<<2048, 256, 0, stream>>>(lstm, wtT, btag, fts);
    crf_kernel<<<64, 512, 0, stream>>>(fts, trans, tags, slens, accb);
    fin_kernel<<<1, 1, 0, stream>>>(accb, out);
}

// Round 11
// 455.485 us; speedup vs baseline: 1.0754x; 1.0754x over previous
//
#include <hip/hip_runtime.h>
#include <hip/hip_fp16.h>

#define B_ 64
#define L_ 128
#define E_ 300
#define HD_ 200
#define H_ 400
#define S_ 50
#define START_ 48
#define END_ 49
#define NG_ 1600
#define BL_ 8192

// ---- ws layout (bytes) ----
// OFF_LSTM region is time-shared: A'(5,242,880)+B'(1,064,960) (prep->xg), then lstm_out (lstm->feat).
// OFF_SH region is time-shared: w8 (prep->lstm, 320,000), then feats (feat->crf, 1,638,400).
#define OFF_XG   0ull                          // bf16 [8192][1600]  26,214,400
#define OFF_LSTM 26214400ull                   // f32  [8192][400]   13,107,200
#define OFF_ABF  OFF_LSTM                      // bf16 [8192][320]    5,242,880 (overlay)
#define OFF_BBF  (OFF_LSTM + 5242880ull)       // bf16 [1664][320]    1,064,960 (overlay)
#define OFF_SH   (OFF_LSTM + 13107200ull)      // max(w8 320,000 ; feats 1,638,400)
#define OFF_INV  (OFF_SH + 1638400ull)         // f32 [1600]  6,400
#define OFF_WTT  (OFF_INV + 6400ull)           // f32 [400][50] 80,000
#define OFF_BIA  (OFF_WTT + 80000ull)          // f32 [1600]  6,400
#define OFF_PART (OFF_BIA + 6400ull)           // f32 [64] per-batch partials (fully rewritten each call)

#define NA_T 2621440   // 8192*320
#define NB_T 532480    // 1664*320
// prep work items = NA_T + NB_T + 1600 (w8 rows) + 20000 (wtagT) + 1600 (biasC) = 3,177,120
// grid 12411*256 = 3,177,216 >= 3,177,120  (round-10 bug: 12409 was 417 short -> stale acc/bias)
#define PREP_BLOCKS 12411

typedef __attribute__((ext_vector_type(8))) short short8;
typedef __attribute__((ext_vector_type(4))) float f32x4;

__device__ __forceinline__ unsigned short f32_to_bf16(float f) {
    unsigned u = __float_as_uint(f);
    unsigned r = u + 0x7fffu + ((u >> 16) & 1u);
    return (unsigned short)(r >> 16);
}
__device__ __forceinline__ float bf16_to_f32(unsigned short s) {
    return __uint_as_float(((unsigned)s) << 16);
}
// 4-wide int8 dot with i32 accumulate: v_dot4_i32_i8 (fallback: manual sext).
__device__ __forceinline__ int dot4(unsigned a, unsigned b, int c) {
#if __has_builtin(__builtin_amdgcn_sdot4)
    return __builtin_amdgcn_sdot4(a, b, c, false);
#else
    c += (int)(signed char)(a)       * (int)(signed char)(b);
    c += (int)(signed char)(a >> 8)  * (int)(signed char)(b >> 8);
    c += (int)(signed char)(a >> 16) * (int)(signed char)(b >> 16);
    c += (int)(signed char)(a >> 24) * (int)(signed char)(b >> 24);
    return c;
#endif
}

// ---------------- mega-prep: A' gather->bf16(padded 320), B' weights->bf16,
// w_hh -> int8 [dir][row(800)][k(200)] with per-row scale, wtagT, biasC.
__global__ void prep_kernel(const int* __restrict__ words, const float* __restrict__ emb,
                            const float* __restrict__ wihf, const float* __restrict__ wihb,
                            const float* __restrict__ bfc, const float* __restrict__ bbc,
                            const float* __restrict__ whh_f, const float* __restrict__ whh_b,
                            const float* __restrict__ wtag,
                            unsigned short* __restrict__ Abf, unsigned short* __restrict__ Bbf,
                            signed char* __restrict__ w8, float* __restrict__ invs,
                            float* __restrict__ wtagT, float* __restrict__ biasC) {
    long g = (long)blockIdx.x * 256 + threadIdx.x;
    if (g < NA_T) {
        int i = (int)(g / 320), k = (int)(g % 320);
        float v = (k < E_) ? emb[(long)words[i] * E_ + k] : 0.f;
        Abf[g] = f32_to_bf16(v);
        return;
    }
    g -= NA_T;
    if (g < NB_T) {
        int r = (int)(g / 320), k = (int)(g % 320);
        float v = 0.f;
        if (r < NG_ && k < E_) v = (r < 800) ? wihf[r * E_ + k] : wihb[(r - 800) * E_ + k];
        Bbf[g] = f32_to_bf16(v);
        return;
    }
    g -= NB_T;
    if (g < 1600) {
        int dir = (int)(g / 800), row = (int)(g % 800);
        const float* w = (dir ? whh_b : whh_f) + row * HD_;
        float m = 1e-20f;
        for (int k = 0; k < HD_; ++k) m = fmaxf(m, fabsf(w[k]));
        float s = 127.f / m;
        signed char* dst = w8 + dir * 160000 + row * HD_;
        for (int k = 0; k < HD_; ++k) dst[k] = (signed char)(int)rintf(w[k] * s);
        invs[g] = m / 16129.f;   // m/(127*127): dequant for int-dot with h scale 127
        return;
    }
    g -= 1600;
    if (g < 20000) {
        int k = (int)(g / S_), s = (int)(g % S_);
        wtagT[g] = wtag[s * H_ + k];
        return;
    }
    g -= 20000;
    if (g < 1600) { biasC[g] = (g < 800) ? bfc[g] : bbc[g - 800]; return; }
}

// ---------------- xg GEMM (MFMA bf16), staged from PRE-CONVERTED bf16 A'/B'.
__global__ __launch_bounds__(256) void xg_gemm(const unsigned short* __restrict__ Abf,
                                               const unsigned short* __restrict__ Bbf,
                                               const float* __restrict__ biasC,
                                               unsigned short* __restrict__ xg) {
    __shared__ unsigned short As[128 * 40];
    __shared__ unsigned short Bs[128 * 40];
    int tid = threadIdx.x;
    int bm = blockIdx.y * 128;
    int bn = blockIdx.x * 128;
    int srow = tid >> 1, half = tid & 1;
    int lane = tid & 63, wave = tid >> 6, r16 = lane & 15, kh = lane >> 4;

    f32x4 acc[2][8];
#pragma unroll
    for (int mi = 0; mi < 2; ++mi)
#pragma unroll
        for (int ni = 0; ni < 8; ++ni) acc[mi][ni] = (f32x4){0.f, 0.f, 0.f, 0.f};

    const unsigned short* Ar = Abf + (long)(bm + srow) * 320;
    const unsigned short* Br = Bbf + (long)(bn + srow) * 320;

    for (int k0 = 0; k0 < 320; k0 += 32) {
#pragma unroll
        for (int j = 0; j < 2; ++j) {
            int off = half * 16 + j * 8;
            *(uint4*)&As[srow * 40 + off] = *(const uint4*)(Ar + k0 + off);
            *(uint4*)&Bs[srow * 40 + off] = *(const uint4*)(Br + k0 + off);
        }
        __syncthreads();
        short8 af[2], bfv[8];
#pragma unroll
        for (int mi = 0; mi < 2; ++mi)
            af[mi] = *(const short8*)&As[(wave * 32 + mi * 16 + r16) * 40 + kh * 8];
#pragma unroll
        for (int ni = 0; ni < 8; ++ni)
            bfv[ni] = *(const short8*)&Bs[(ni * 16 + r16) * 40 + kh * 8];
#pragma unroll
        for (int mi = 0; mi < 2; ++mi)
#pragma unroll
            for (int ni = 0; ni < 8; ++ni)
                acc[mi][ni] = __builtin_amdgcn_mfma_f32_16x16x32_bf16(af[mi], bfv[ni], acc[mi][ni], 0, 0, 0);
        __syncthreads();
    }
#pragma unroll
    for (int ni = 0; ni < 8; ++ni) {
        int g = bn + ni * 16 + r16;
        if (g < NG_) {
            float bias = biasC[g];
#pragma unroll
            for (int mi = 0; mi < 2; ++mi) {
#pragma unroll
                for (int r = 0; r < 4; ++r) {
                    int row = bm + wave * 32 + mi * 16 + kh * 4 + r;
                    xg[(long)row * NG_ + g] = f32_to_bf16(acc[mi][ni][r] + bias);
                }
            }
        }
    }
}

// ---------------- LSTM recurrence: block=(dir,b), 832 thr (800 active), int8 weights
// FULLY LDS-RESIDENT (160,000 B = whole direction). Thread tid owns gate row tid.
// Per step: 25 ds_read_b64 (row int8) + 25 broadcast b64 (h int8) + 50 v_dot4_i32_i8.
// h requantized to +-127 each step (h in (-1,1) strictly). VGPR ~48: no spill possible.
__global__ __launch_bounds__(832) void lstm_rec(const unsigned short* __restrict__ xg,
                                                const signed char* __restrict__ w8,
                                                const float* __restrict__ invs,
                                                float* __restrict__ lstm_out) {
    __shared__ __align__(16) unsigned char lds[163456];
    signed char* wl = (signed char*)lds;             // [800][200] int8
    unsigned char* h8 = lds + 160000;                // 200 B int8 h (pad to 256)
    float* a_lds = (float*)(lds + 160256);           // 800 f32 gate activations
    int tid = threadIdx.x;
    int dir = blockIdx.x >> 6;
    int b = blockIdx.x & 63;
    bool act = tid < 800;
    int q = tid / 200;   // 0=i 1=f 2=g 3=o

    // stage the direction's full weight matrix into LDS (160,000 B = 10,000 uint4)
    {
        const uint4* src = (const uint4*)(w8 + dir * 160000);
        uint4* dst = (uint4*)wl;
        for (int i = tid; i < 10000; i += 832) dst[i] = src[i];
    }
    float invsc = act ? invs[dir * 800 + tid] : 0.f;
    if (tid < 50) ((unsigned*)h8)[tid] = 0u;   // h=0 -> q=0
    float c = 0.f;
    __syncthreads();

    const uint2* hv2 = (const uint2*)h8;                             // 25 broadcast chunks
    const uint2* wrow = (const uint2*)(wl + (act ? tid : 0) * HD_);  // 8-aligned (200%8==0)
    const unsigned short* xbase = xg + (long)b * L_ * NG_ + dir * 800;

    int t0 = dir ? (L_ - 1) : 0;
    float x = act ? bf16_to_f32(xbase[(long)t0 * NG_ + tid]) : 0.f;

    for (int step = 0; step < L_; ++step) {
        int t = dir ? (L_ - 1 - step) : step;
        float x_n = 0.f;
        if (act && step + 1 < L_) {
            int tn = dir ? (t - 1) : (t + 1);
            x_n = bf16_to_f32(xbase[(long)tn * NG_ + tid]);
        }
        if (act) {
            int di = 0;
#pragma unroll
            for (int j = 0; j < 25; ++j) {
                uint2 wv = wrow[j];
                uint2 hh = hv2[j];
                di = dot4(wv.x, hh.x, di);
                di = dot4(wv.y, hh.y, di);
            }
            float p = x + (float)di * invsc;
            float av;
            if (q == 2) {
                float e = __expf(-2.f * p);          // tanh
                av = 2.f / (1.f + e) - 1.f;
            } else {
                av = 1.f / (1.f + __expf(-p));       // sigmoid
            }
            a_lds[tid] = av;
        }
        __syncthreads();
        if (tid < HD_) {
            float ig = a_lds[tid];
            float fg = a_lds[200 + tid];
            float gg = a_lds[400 + tid];
            float og = a_lds[600 + tid];
            c = fg * c + ig * gg;
            float ec = __expf(-2.f * c);
            float hn = og * (2.f / (1.f + ec) - 1.f);
            ((signed char*)h8)[tid] = (signed char)(int)rintf(hn * 127.f);
            lstm_out[((long)(b * L_ + t)) * H_ + dir * HD_ + tid] = hn;
        }
        x = x_n;
        __syncthreads();
    }
}

// ---------------- features = lstm_out @ W_tag^T + b_tag (unchanged)
__global__ __launch_bounds__(256) void feat_kernel(const float* __restrict__ lstm_out,
                                                   const float* __restrict__ wtagT,
                                                   const float* __restrict__ btag,
                                                   float* __restrict__ feats) {
    __shared__ float hrow[4 * H_];
    int tid = threadIdx.x;
    int base = blockIdx.x * 4;
    for (int idx = tid; idx < 4 * H_; idx += 256)
        hrow[idx] = lstm_out[(long)base * H_ + idx];
    __syncthreads();
    int il = tid >> 6, s = tid & 63;
    if (s < S_) {
        float acc = btag[s];
        const float* hr = hrow + il * H_;
#pragma unroll 4
        for (int k = 0; k < H_; ++k)
            acc = fmaf(hr[k], wtagT[k * S_ + s], acc);
        feats[(base + il) * S_ + s] = acc;
    }
}

// ---------------- CRF forward + labeled score. Block=batch, 512 thr: j=tid>>3, 8 lanes/j.
// Writes a per-batch partial (fully rewritten every call -> no cross-call state, no atomics).
__global__ __launch_bounds__(512) void crf_kernel(const float* __restrict__ feats,
                                                  const float* __restrict__ trans,
                                                  const int* __restrict__ tags,
                                                  const int* __restrict__ seqlens,
                                                  float* __restrict__ part) {
    __shared__ float Tt[S_ * S_];   // Tt[j*50+i] = trans[i*50+j]
    __shared__ float alpha[S_];
    __shared__ float lastal[S_];
    __shared__ int tg[L_];
    int tid = threadIdx.x;
    int b = blockIdx.x;
    for (int idx = tid; idx < S_ * S_; idx += 512) {
        int j = idx / S_, i = idx % S_;
        Tt[idx] = trans[i * S_ + j];
    }
    if (tid < L_) tg[tid] = tags[b * L_ + tid];
    int slen = seqlens[b];
    const float* fb = feats + (long)b * L_ * S_;
    __syncthreads();
    if (tid < S_) {
        float a = Tt[tid * S_ + START_] + fb[tid];
        alpha[tid] = a;
        if (slen == 1) lastal[tid] = a;
    }
    __syncthreads();
    int j = tid >> 3, sub = tid & 7;
    bool jact = j < S_;
    for (int t = 1; t < L_; ++t) {
        float anew = 0.f;
        if (jact) {
            float m = -1e30f;
            for (int i = sub; i < S_; i += 8) m = fmaxf(m, alpha[i] + Tt[j * S_ + i]);
            m = fmaxf(m, __shfl_xor(m, 1));
            m = fmaxf(m, __shfl_xor(m, 2));
            m = fmaxf(m, __shfl_xor(m, 4));
            float s = 0.f;
            for (int i = sub; i < S_; i += 8) s += __expf(alpha[i] + Tt[j * S_ + i] - m);
            s += __shfl_xor(s, 1);
            s += __shfl_xor(s, 2);
            s += __shfl_xor(s, 4);
            anew = m + __logf(s) + fb[t * S_ + j];
        }
        __syncthreads();
        if (jact && sub == 0) {
            alpha[j] = anew;
            if (t == slen - 1) lastal[j] = anew;
        }
        __syncthreads();
    }
    if (tid < 64) {
        float la = (tid < S_) ? (lastal[tid] + Tt[END_ * S_ + tid]) : -1e30f;
        float m = la;
        for (int off = 32; off; off >>= 1) m = fmaxf(m, __shfl_xor(m, off));
        float e = (tid < S_) ? __expf(la - m) : 0.f;
        for (int off = 32; off; off >>= 1) e += __shfl_xor(e, off);
        float unl = m + __logf(e);
        float lab = 0.f;
        for (int tt = tid; tt < L_; tt += 64) {
            if (tt == 0) {
                lab += Tt[tg[0] * S_ + START_] + fb[tg[0]];
            } else if (tt < slen) {
                lab += Tt[tg[tt] * S_ + tg[tt - 1]] + fb[tt * S_ + tg[tt]];
            }
        }
        if (tid == 0) lab += Tt[END_ * S_ + tg[slen - 1]];
        for (int off = 32; off; off >>= 1) lab += __shfl_xor(lab, off);
        if (tid == 0) part[b] = unl - lab;
    }
}

// ---------------- final: deterministic fixed-order sum of 64 partials
__global__ void fin_kernel(const float* __restrict__ part, float* __restrict__ out) {
    float s = 0.f;
    for (int i = 0; i < B_; ++i) s += part[i];
    out[0] = s;
}

extern "C" void kernel_launch(void* const* d_in, const int* in_sizes, int n_in,
                              void* d_out, int out_size, void* d_ws, size_t ws_size,
                              hipStream_t stream) {
    const int*   words = (const int*)d_in[0];
    const int*   slens = (const int*)d_in[1];
    // d_in[2] = masks: semantically (t < seq_len); not read.
    const int*   tags  = (const int*)d_in[3];
    const float* emb   = (const float*)d_in[4];
    const float* wihf  = (const float*)d_in[5];
    const float* whhf  = (const float*)d_in[6];
    const float* bf    = (const float*)d_in[7];
    const float* wihb  = (const float*)d_in[8];
    const float* whhb  = (const float*)d_in[9];
    const float* bb    = (const float*)d_in[10];
    const float* wtag  = (const float*)d_in[11];
    const float* btag  = (const float*)d_in[12];
    const float* trans = (const float*)d_in[13];

    char* ws = (char*)d_ws;
    unsigned short* xg   = (unsigned short*)(ws + OFF_XG);
    float*          lstm = (float*)(ws + OFF_LSTM);
    unsigned short* Abf  = (unsigned short*)(ws + OFF_ABF);  // prep -> xg (overlays lstm)
    unsigned short* Bbf  = (unsigned short*)(ws + OFF_BBF);  // prep -> xg (overlays lstm)
    signed char*    w8   = (signed char*)(ws + OFF_SH);      // prep -> lstm
    float*          fts  = (float*)(ws + OFF_SH);            // feat -> crf (time-shared)
    float*          invs = (float*)(ws + OFF_INV);
    float*          wtT  = (float*)(ws + OFF_WTT);
    float*          biaC = (float*)(ws + OFF_BIA);
    float*          part = (float*)(ws + OFF_PART);
    float*          out  = (float*)d_out;

    prep_kernel<<<PREP_BLOCKS, 256, 0, stream>>>(words, emb, wihf, wihb, bf, bb, whhf, whhb,
                                                 wtag, Abf, Bbf, w8, invs, wtT, biaC);
    xg_gemm<<<dim3(13, 64), 256, 0, stream>>>(Abf, Bbf, biaC, xg);
    lstm_rec<<<128, 832, 0, stream>>>(xg, w8, invs, lstm);
    feat_kernel<<<2048, 256, 0, stream>>>(lstm, wtT, btag, fts);
    crf_kernel<<<64, 512, 0, stream>>>(fts, trans, tags, slens, part);
    fin_kernel<<<1, 1, 0, stream>>>(part, out);
}

// Round 12
// 392.895 us; speedup vs baseline: 1.2467x; 1.1593x over previous
//
#include <hip/hip_runtime.h>
#include <hip/hip_fp16.h>

#define B_ 64
#define L_ 128
#define E_ 300
#define HD_ 200
#define H_ 400
#define S_ 50
#define START_ 48
#define END_ 49
#define NG_ 1600
#define BL_ 8192

// ---- ws layout (bytes) ----
#define OFF_XG   0ull                          // bf16 [8192][1600]  26,214,400
#define OFF_LSTM 26214400ull                   // f32  [8192][400]   13,107,200
#define OFF_ABF  OFF_LSTM                      // bf16 [8192][320]    5,242,880 (overlay)
#define OFF_BBF  (OFF_LSTM + 5242880ull)       // bf16 [1664][320]    1,064,960 (overlay)
#define OFF_SH   (OFF_LSTM + 13107200ull)      // max(w8 320,000 ; feats 1,638,400)
#define OFF_INV  (OFF_SH + 1638400ull)         // f32 [1600]  6,400
#define OFF_WTT  (OFF_INV + 6400ull)           // f32 [400][50] 80,000
#define OFF_BIA  (OFF_WTT + 80000ull)          // f32 [1600]  6,400
#define OFF_PART (OFF_BIA + 6400ull)           // f32 [64] per-batch partials

#define NA_T 2621440   // 8192*320
#define NB_T 532480    // 1664*320
// prep items = NA_T + NB_T + 20000 (wtagT) + 1600 (biasC) = 3,175,520
// grid 12405*256 = 3,175,680 >= 3,175,520   (w8 quant moved to quant_kernel)
#define PREP_BLOCKS 12405

typedef __attribute__((ext_vector_type(8))) short short8;
typedef __attribute__((ext_vector_type(4))) float f32x4;

__device__ __forceinline__ unsigned short f32_to_bf16(float f) {
    unsigned u = __float_as_uint(f);
    unsigned r = u + 0x7fffu + ((u >> 16) & 1u);
    return (unsigned short)(r >> 16);
}
__device__ __forceinline__ float bf16_to_f32(unsigned short s) {
    return __uint_as_float(((unsigned)s) << 16);
}
// 4-wide int8 dot with i32 accumulate: v_dot4_i32_i8 (fallback: manual sext).
__device__ __forceinline__ int dot4(unsigned a, unsigned b, int c) {
#if __has_builtin(__builtin_amdgcn_sdot4)
    return __builtin_amdgcn_sdot4(a, b, c, false);
#else
    c += (int)(signed char)(a)       * (int)(signed char)(b);
    c += (int)(signed char)(a >> 8)  * (int)(signed char)(b >> 8);
    c += (int)(signed char)(a >> 16) * (int)(signed char)(b >> 16);
    c += (int)(signed char)(a >> 24) * (int)(signed char)(b >> 24);
    return c;
#endif
}

// ---------------- prep: A' gather->bf16(padded 320), B' weights->bf16, wtagT, biasC.
__global__ void prep_kernel(const int* __restrict__ words, const float* __restrict__ emb,
                            const float* __restrict__ wihf, const float* __restrict__ wihb,
                            const float* __restrict__ bfc, const float* __restrict__ bbc,
                            const float* __restrict__ wtag,
                            unsigned short* __restrict__ Abf, unsigned short* __restrict__ Bbf,
                            float* __restrict__ wtagT, float* __restrict__ biasC) {
    long g = (long)blockIdx.x * 256 + threadIdx.x;
    if (g < NA_T) {
        int i = (int)(g / 320), k = (int)(g % 320);
        float v = (k < E_) ? emb[(long)words[i] * E_ + k] : 0.f;
        Abf[g] = f32_to_bf16(v);
        return;
    }
    g -= NA_T;
    if (g < NB_T) {
        int r = (int)(g / 320), k = (int)(g % 320);
        float v = 0.f;
        if (r < NG_ && k < E_) v = (r < 800) ? wihf[r * E_ + k] : wihb[(r - 800) * E_ + k];
        Bbf[g] = f32_to_bf16(v);
        return;
    }
    g -= NB_T;
    if (g < 20000) {
        int k = (int)(g / S_), s = (int)(g % S_);
        wtagT[g] = wtag[s * H_ + k];
        return;
    }
    g -= 20000;
    if (g < 1600) { biasC[g] = (g < 800) ? bfc[g] : bbc[g - 800]; return; }
}

// ---------------- w_hh quant: one WAVE per row (was 400 serial loads/thread in prep).
// Global w8 layout = LSTM's LDS layout (k-major chunks, straight-copy stageable):
//   [dir] { chunks [j=0..11][row 0..799] uint4 (k=16j..16j+15) at (j*800+row)*16,
//           tails  [row] uint2 (k=192..199) at 153600 + row*8 }   (160,000 B per dir)
__global__ __launch_bounds__(256) void quant_kernel(const float* __restrict__ whh_f,
                                                    const float* __restrict__ whh_b,
                                                    signed char* __restrict__ w8,
                                                    float* __restrict__ invs) {
    int gw = (int)((blockIdx.x * 256 + threadIdx.x) >> 6);
    int lane = threadIdx.x & 63;
    if (gw >= 1600) return;
    int dir = gw / 800, row = gw % 800;
    const float* w = (dir ? whh_b : whh_f) + row * HD_;
    float m = 1e-20f;
    for (int k = lane; k < HD_; k += 64) m = fmaxf(m, fabsf(w[k]));
    for (int off = 32; off; off >>= 1) m = fmaxf(m, __shfl_xor(m, off));
    float s = 127.f / m;
    if (lane < 50) {
        int k0 = lane * 4;
        unsigned pk = 0;
#pragma unroll
        for (int i = 0; i < 4; ++i) {
            int v = (int)rintf(w[k0 + i] * s);
            pk |= ((unsigned)(v & 0xff)) << (8 * i);
        }
        unsigned char* base = (unsigned char*)w8 + dir * 160000;
        if (lane < 48) {
            int j = lane >> 2, wsel = lane & 3;
            *(unsigned*)(base + (size_t)(j * 800 + row) * 16 + wsel * 4) = pk;
        } else {
            *(unsigned*)(base + 153600 + (size_t)row * 8 + (lane - 48) * 4) = pk;
        }
    }
    if (lane == 0) invs[gw] = m / 16129.f;   // m/(127*127)
}

// ---------------- xg GEMM (MFMA bf16), staged from pre-converted bf16 A'/B'. (unchanged)
__global__ __launch_bounds__(256) void xg_gemm(const unsigned short* __restrict__ Abf,
                                               const unsigned short* __restrict__ Bbf,
                                               const float* __restrict__ biasC,
                                               unsigned short* __restrict__ xg) {
    __shared__ unsigned short As[128 * 40];
    __shared__ unsigned short Bs[128 * 40];
    int tid = threadIdx.x;
    int bm = blockIdx.y * 128;
    int bn = blockIdx.x * 128;
    int srow = tid >> 1, half = tid & 1;
    int lane = tid & 63, wave = tid >> 6, r16 = lane & 15, kh = lane >> 4;

    f32x4 acc[2][8];
#pragma unroll
    for (int mi = 0; mi < 2; ++mi)
#pragma unroll
        for (int ni = 0; ni < 8; ++ni) acc[mi][ni] = (f32x4){0.f, 0.f, 0.f, 0.f};

    const unsigned short* Ar = Abf + (long)(bm + srow) * 320;
    const unsigned short* Br = Bbf + (long)(bn + srow) * 320;

    for (int k0 = 0; k0 < 320; k0 += 32) {
#pragma unroll
        for (int j = 0; j < 2; ++j) {
            int off = half * 16 + j * 8;
            *(uint4*)&As[srow * 40 + off] = *(const uint4*)(Ar + k0 + off);
            *(uint4*)&Bs[srow * 40 + off] = *(const uint4*)(Br + k0 + off);
        }
        __syncthreads();
        short8 af[2], bfv[8];
#pragma unroll
        for (int mi = 0; mi < 2; ++mi)
            af[mi] = *(const short8*)&As[(wave * 32 + mi * 16 + r16) * 40 + kh * 8];
#pragma unroll
        for (int ni = 0; ni < 8; ++ni)
            bfv[ni] = *(const short8*)&Bs[(ni * 16 + r16) * 40 + kh * 8];
#pragma unroll
        for (int mi = 0; mi < 2; ++mi)
#pragma unroll
            for (int ni = 0; ni < 8; ++ni)
                acc[mi][ni] = __builtin_amdgcn_mfma_f32_16x16x32_bf16(af[mi], bfv[ni], acc[mi][ni], 0, 0, 0);
        __syncthreads();
    }
#pragma unroll
    for (int ni = 0; ni < 8; ++ni) {
        int g = bn + ni * 16 + r16;
        if (g < NG_) {
            float bias = biasC[g];
#pragma unroll
            for (int mi = 0; mi < 2; ++mi) {
#pragma unroll
                for (int r = 0; r < 4; ++r) {
                    int row = bm + wave * 32 + mi * 16 + kh * 4 + r;
                    xg[(long)row * NG_ + g] = f32_to_bf16(acc[mi][ni][r] + bias);
                }
            }
        }
    }
}

// ---------------- LSTM recurrence: int8 weights LDS-resident, k-major b128 layout.
// R11 was LDS-issue-bound (650 b64/step/block ~ 2600 clk). Now 13 weight reads/thread
// (12 b128 + 1 b64, conflict-free: consecutive lanes -> consecutive 16B) + 13 h
// broadcasts. ~1450-1800 clk/step expected.
__global__ __launch_bounds__(832) void lstm_rec(const unsigned short* __restrict__ xg,
                                                const signed char* __restrict__ w8,
                                                const float* __restrict__ invs,
                                                float* __restrict__ lstm_out) {
    __shared__ __align__(16) unsigned char lds[163424];
    // [0,153600): weight chunks [12][800] uint4 ; [153600,160000): tails [800] uint2
    // [160000,160224): h8 (12 uint4 + uint2 + pad) ; [160224,163424): a_lds [800] f32
    uint4* wq4 = (uint4*)lds;
    uint2* wt2 = (uint2*)(lds + 153600);
    uint4* h4c = (uint4*)(lds + 160000);
    uint2* ht2 = (uint2*)(lds + 160192);
    float* a_lds = (float*)(lds + 160224);
    int tid = threadIdx.x;
    int dir = blockIdx.x >> 6;
    int b = blockIdx.x & 63;
    bool act = tid < 800;
    int tw = act ? tid : 0;
    int q = tid / 200;   // 0=i 1=f 2=g 3=o

    // stage the direction's weights (global layout == LDS layout: straight copy)
    {
        const uint4* src = (const uint4*)(w8 + dir * 160000);
        uint4* dst = (uint4*)lds;
        for (int i = tid; i < 10000; i += 832) dst[i] = src[i];
    }
    float invsc = act ? invs[dir * 800 + tid] : 0.f;
    if (tid < 56) ((unsigned*)(lds + 160000))[tid] = 0u;   // h=0
    float c = 0.f;
    __syncthreads();

    const unsigned short* xbase = xg + (long)b * L_ * NG_ + dir * 800;
    int t0 = dir ? (L_ - 1) : 0;
    float x = act ? bf16_to_f32(xbase[(long)t0 * NG_ + tid]) : 0.f;

    for (int step = 0; step < L_; ++step) {
        int t = dir ? (L_ - 1 - step) : step;
        float x_n = 0.f;
        if (act && step + 1 < L_) {
            int tn = dir ? (t - 1) : (t + 1);
            x_n = bf16_to_f32(xbase[(long)tn * NG_ + tid]);
        }
        if (act) {
            int di = 0;
#pragma unroll
            for (int j = 0; j < 12; ++j) {
                uint4 wv = wq4[j * 800 + tw];
                uint4 hh = h4c[j];
                di = dot4(wv.x, hh.x, di); di = dot4(wv.y, hh.y, di);
                di = dot4(wv.z, hh.z, di); di = dot4(wv.w, hh.w, di);
            }
            {
                uint2 wv = wt2[tw];
                uint2 hh = ht2[0];
                di = dot4(wv.x, hh.x, di); di = dot4(wv.y, hh.y, di);
            }
            float p = x + (float)di * invsc;
            float av;
            if (q == 2) {
                float e = __expf(-2.f * p);          // tanh
                av = 2.f / (1.f + e) - 1.f;
            } else {
                av = 1.f / (1.f + __expf(-p));       // sigmoid
            }
            a_lds[tid] = av;
        }
        __syncthreads();
        if (tid < HD_) {
            float ig = a_lds[tid];
            float fg = a_lds[200 + tid];
            float gg = a_lds[400 + tid];
            float og = a_lds[600 + tid];
            c = fg * c + ig * gg;
            float ec = __expf(-2.f * c);
            float hn = og * (2.f / (1.f + ec) - 1.f);
            ((signed char*)(lds + 160000))[tid] = (signed char)(int)rintf(hn * 127.f);
            lstm_out[((long)(b * L_ + t)) * H_ + dir * HD_ + tid] = hn;
        }
        x = x_n;
        __syncthreads();
    }
}

// ---------------- features = lstm_out @ W_tag^T + b_tag (unchanged)
__global__ __launch_bounds__(256) void feat_kernel(const float* __restrict__ lstm_out,
                                                   const float* __restrict__ wtagT,
                                                   const float* __restrict__ btag,
                                                   float* __restrict__ feats) {
    __shared__ float hrow[4 * H_];
    int tid = threadIdx.x;
    int base = blockIdx.x * 4;
    for (int idx = tid; idx < 4 * H_; idx += 256)
        hrow[idx] = lstm_out[(long)base * H_ + idx];
    __syncthreads();
    int il = tid >> 6, s = tid & 63;
    if (s < S_) {
        float acc = btag[s];
        const float* hr = hrow + il * H_;
#pragma unroll 4
        for (int k = 0; k < H_; ++k)
            acc = fmaf(hr[k], wtagT[k * S_ + s], acc);
        feats[(base + il) * S_ + s] = acc;
    }
}

// ---------------- CRF forward + labeled score (unchanged; per-batch partials, no atomics)
__global__ __launch_bounds__(512) void crf_kernel(const float* __restrict__ feats,
                                                  const float* __restrict__ trans,
                                                  const int* __restrict__ tags,
                                                  const int* __restrict__ seqlens,
                                                  float* __restrict__ part) {
    __shared__ float Tt[S_ * S_];   // Tt[j*50+i] = trans[i*50+j]
    __shared__ float alpha[S_];
    __shared__ float lastal[S_];
    __shared__ int tg[L_];
    int tid = threadIdx.x;
    int b = blockIdx.x;
    for (int idx = tid; idx < S_ * S_; idx += 512) {
        int j = idx / S_, i = idx % S_;
        Tt[idx] = trans[i * S_ + j];
    }
    if (tid < L_) tg[tid] = tags[b * L_ + tid];
    int slen = seqlens[b];
    const float* fb = feats + (long)b * L_ * S_;
    __syncthreads();
    if (tid < S_) {
        float a = Tt[tid * S_ + START_] + fb[tid];
        alpha[tid] = a;
        if (slen == 1) lastal[tid] = a;
    }
    __syncthreads();
    int j = tid >> 3, sub = tid & 7;
    bool jact = j < S_;
    for (int t = 1; t < L_; ++t) {
        float anew = 0.f;
        if (jact) {
            float m = -1e30f;
            for (int i = sub; i < S_; i += 8) m = fmaxf(m, alpha[i] + Tt[j * S_ + i]);
            m = fmaxf(m, __shfl_xor(m, 1));
            m = fmaxf(m, __shfl_xor(m, 2));
            m = fmaxf(m, __shfl_xor(m, 4));
            float s = 0.f;
            for (int i = sub; i < S_; i += 8) s += __expf(alpha[i] + Tt[j * S_ + i] - m);
            s += __shfl_xor(s, 1);
            s += __shfl_xor(s, 2);
            s += __shfl_xor(s, 4);
            anew = m + __logf(s) + fb[t * S_ + j];
        }
        __syncthreads();
        if (jact && sub == 0) {
            alpha[j] = anew;
            if (t == slen - 1) lastal[j] = anew;
        }
        __syncthreads();
    }
    if (tid < 64) {
        float la = (tid < S_) ? (lastal[tid] + Tt[END_ * S_ + tid]) : -1e30f;
        float m = la;
        for (int off = 32; off; off >>= 1) m = fmaxf(m, __shfl_xor(m, off));
        float e = (tid < S_) ? __expf(la - m) : 0.f;
        for (int off = 32; off; off >>= 1) e += __shfl_xor(e, off);
        float unl = m + __logf(e);
        float lab = 0.f;
        for (int tt = tid; tt < L_; tt += 64) {
            if (tt == 0) {
                lab += Tt[tg[0] * S_ + START_] + fb[tg[0]];
            } else if (tt < slen) {
                lab += Tt[tg[tt] * S_ + tg[tt - 1]] + fb[tt * S_ + tg[tt]];
            }
        }
        if (tid == 0) lab += Tt[END_ * S_ + tg[slen - 1]];
        for (int off = 32; off; off >>= 1) lab += __shfl_xor(lab, off);
        if (tid == 0) part[b] = unl - lab;
    }
}

// ---------------- final: deterministic fixed-order sum of 64 partials
__global__ void fin_kernel(const float* __restrict__ part, float* __restrict__ out) {
    float s = 0.f;
    for (int i = 0; i < B_; ++i) s += part[i];
    out[0] = s;
}

extern "C" void kernel_launch(void* const* d_in, const int* in_sizes, int n_in,
                              void* d_out, int out_size, void* d_ws, size_t ws_size,
                              hipStream_t stream) {
    const int*   words = (const int*)d_in[0];
    const int*   slens = (const int*)d_in[1];
    // d_in[2] = masks: semantically (t < seq_len); not read.
    const int*   tags  = (const int*)d_in[3];
    const float* emb   = (const float*)d_in[4];
    const float* wihf  = (const float*)d_in[5];
    const float* whhf  = (const float*)d_in[6];
    const float* bf    = (const float*)d_in[7];
    const float* wihb  = (const float*)d_in[8];
    const float* whhb  = (const float*)d_in[9];
    const float* bb    = (const float*)d_in[10];
    const float* wtag  = (const float*)d_in[11];
    const float* btag  = (const float*)d_in[12];
    const float* trans = (const float*)d_in[13];

    char* ws = (char*)d_ws;
    unsigned short* xg   = (unsigned short*)(ws + OFF_XG);
    float*          lstm = (float*)(ws + OFF_LSTM);
    unsigned short* Abf  = (unsigned short*)(ws + OFF_ABF);  // prep -> xg (overlays lstm)
    unsigned short* Bbf  = (unsigned short*)(ws + OFF_BBF);  // prep -> xg (overlays lstm)
    signed char*    w8   = (signed char*)(ws + OFF_SH);      // quant -> lstm
    float*          fts  = (float*)(ws + OFF_SH);            // feat -> crf (time-shared)
    float*          invs = (float*)(ws + OFF_INV);
    float*          wtT  = (float*)(ws + OFF_WTT);
    float*          biaC = (float*)(ws + OFF_BIA);
    float*          part = (float*)(ws + OFF_PART);
    float*          out  = (float*)d_out;

    prep_kernel<<<PREP_BLOCKS, 256, 0, stream>>>(words, emb, wihf, wihb, bf, bb,
                                                 wtag, Abf, Bbf, wtT, biaC);
    quant_kernel<<<400, 256, 0, stream>>>(whhf, whhb, w8, invs);
    xg_gemm<<<dim3(13, 64), 256, 0, stream>>>(Abf, Bbf, biaC, xg);
    lstm_rec<<<128, 832, 0, stream>>>(xg, w8, invs, lstm);
    feat_kernel<<<2048, 256, 0, stream>>>(lstm, wtT, btag, fts);
    crf_kernel<<<64, 512, 0, stream>>>(fts, trans, tags, slens, part);
    fin_kernel<<<1, 1, 0, stream>>>(part, out);
}

// Round 13
// 375.082 us; speedup vs baseline: 1.3060x; 1.0475x over previous
//
#include <hip/hip_runtime.h>
#include <hip/hip_fp16.h>

#define B_ 64
#define L_ 128
#define E_ 300
#define HD_ 200
#define H_ 400
#define S_ 50
#define START_ 48
#define END_ 49
#define NG_ 1600
#define BL_ 8192

// ---- ws layout (bytes) ----
#define OFF_XG   0ull                          // bf16 [8192][1600]  26,214,400
#define OFF_LSTM 26214400ull                   // f32  [8192][400]   13,107,200
#define OFF_ABF  OFF_LSTM                      // bf16 [8192][320]    5,242,880 (overlay)
#define OFF_BBF  (OFF_LSTM + 5242880ull)       // bf16 [1664][320]    1,064,960 (overlay)
#define OFF_SH   (OFF_LSTM + 13107200ull)      // max(w8 320,000 ; feats 1,638,400)
#define OFF_INV  (OFF_SH + 1638400ull)         // f32 [1600]  6,400
#define OFF_WTT  (OFF_INV + 6400ull)           // f32 [400][50] 80,000
#define OFF_BIA  (OFF_WTT + 80000ull)          // f32 [1600]  6,400
#define OFF_PART (OFF_BIA + 6400ull)           // f32 [64] per-batch partials

#define NA_T 2621440   // 8192*320
#define NB_T 532480    // 1664*320
// prep items = NA_T + NB_T + 20000 (wtagT) + 1600 (biasC) = 3,175,520
// grid 12405*256 = 3,175,680 >= 3,175,520
#define PREP_BLOCKS 12405

typedef __attribute__((ext_vector_type(8))) short short8;
typedef __attribute__((ext_vector_type(4))) float f32x4;

__device__ __forceinline__ unsigned short f32_to_bf16(float f) {
    unsigned u = __float_as_uint(f);
    unsigned r = u + 0x7fffu + ((u >> 16) & 1u);
    return (unsigned short)(r >> 16);
}
__device__ __forceinline__ float bf16_to_f32(unsigned short s) {
    return __uint_as_float(((unsigned)s) << 16);
}
// 4-wide int8 dot with i32 accumulate: v_dot4_i32_i8 (fallback: manual sext).
__device__ __forceinline__ int dot4(unsigned a, unsigned b, int c) {
#if __has_builtin(__builtin_amdgcn_sdot4)
    return __builtin_amdgcn_sdot4(a, b, c, false);
#else
    c += (int)(signed char)(a)       * (int)(signed char)(b);
    c += (int)(signed char)(a >> 8)  * (int)(signed char)(b >> 8);
    c += (int)(signed char)(a >> 16) * (int)(signed char)(b >> 16);
    c += (int)(signed char)(a >> 24) * (int)(signed char)(b >> 24);
    return c;
#endif
}

// ---------------- prep: A' gather->bf16(padded 320), B' weights->bf16, wtagT, biasC.
__global__ void prep_kernel(const int* __restrict__ words, const float* __restrict__ emb,
                            const float* __restrict__ wihf, const float* __restrict__ wihb,
                            const float* __restrict__ bfc, const float* __restrict__ bbc,
                            const float* __restrict__ wtag,
                            unsigned short* __restrict__ Abf, unsigned short* __restrict__ Bbf,
                            float* __restrict__ wtagT, float* __restrict__ biasC) {
    long g = (long)blockIdx.x * 256 + threadIdx.x;
    if (g < NA_T) {
        int i = (int)(g / 320), k = (int)(g % 320);
        float v = (k < E_) ? emb[(long)words[i] * E_ + k] : 0.f;
        Abf[g] = f32_to_bf16(v);
        return;
    }
    g -= NA_T;
    if (g < NB_T) {
        int r = (int)(g / 320), k = (int)(g % 320);
        float v = 0.f;
        if (r < NG_ && k < E_) v = (r < 800) ? wihf[r * E_ + k] : wihb[(r - 800) * E_ + k];
        Bbf[g] = f32_to_bf16(v);
        return;
    }
    g -= NB_T;
    if (g < 20000) {
        int k = (int)(g / S_), s = (int)(g % S_);
        wtagT[g] = wtag[s * H_ + k];
        return;
    }
    g -= 20000;
    if (g < 1600) { biasC[g] = (g < 800) ? bfc[g] : bbc[g - 800]; return; }
}

// ---------------- w_hh quant: one WAVE per row. Global w8 layout (k-major chunks):
//   [dir] { chunks [j=0..11][row 0..799] uint4 (k=16j..16j+15) at (j*800+row)*16,
//           tails  [row] uint2 (k=192..199) at 153600 + row*8 }   (160,000 B per dir)
__global__ __launch_bounds__(256) void quant_kernel(const float* __restrict__ whh_f,
                                                    const float* __restrict__ whh_b,
                                                    signed char* __restrict__ w8,
                                                    float* __restrict__ invs) {
    int gw = (int)((blockIdx.x * 256 + threadIdx.x) >> 6);
    int lane = threadIdx.x & 63;
    if (gw >= 1600) return;
    int dir = gw / 800, row = gw % 800;
    const float* w = (dir ? whh_b : whh_f) + row * HD_;
    float m = 1e-20f;
    for (int k = lane; k < HD_; k += 64) m = fmaxf(m, fabsf(w[k]));
    for (int off = 32; off; off >>= 1) m = fmaxf(m, __shfl_xor(m, off));
    float s = 127.f / m;
    if (lane < 50) {
        int k0 = lane * 4;
        unsigned pk = 0;
#pragma unroll
        for (int i = 0; i < 4; ++i) {
            int v = (int)rintf(w[k0 + i] * s);
            pk |= ((unsigned)(v & 0xff)) << (8 * i);
        }
        unsigned char* base = (unsigned char*)w8 + dir * 160000;
        if (lane < 48) {
            int j = lane >> 2, wsel = lane & 3;
            *(unsigned*)(base + (size_t)(j * 800 + row) * 16 + wsel * 4) = pk;
        } else {
            *(unsigned*)(base + 153600 + (size_t)row * 8 + (lane - 48) * 4) = pk;
        }
    }
    if (lane == 0) invs[gw] = m / 16129.f;   // m/(127*127)
}

// ---------------- xg GEMM (MFMA bf16), staged from pre-converted bf16 A'/B'. (unchanged)
__global__ __launch_bounds__(256) void xg_gemm(const unsigned short* __restrict__ Abf,
                                               const unsigned short* __restrict__ Bbf,
                                               const float* __restrict__ biasC,
                                               unsigned short* __restrict__ xg) {
    __shared__ unsigned short As[128 * 40];
    __shared__ unsigned short Bs[128 * 40];
    int tid = threadIdx.x;
    int bm = blockIdx.y * 128;
    int bn = blockIdx.x * 128;
    int srow = tid >> 1, half = tid & 1;
    int lane = tid & 63, wave = tid >> 6, r16 = lane & 15, kh = lane >> 4;

    f32x4 acc[2][8];
#pragma unroll
    for (int mi = 0; mi < 2; ++mi)
#pragma unroll
        for (int ni = 0; ni < 8; ++ni) acc[mi][ni] = (f32x4){0.f, 0.f, 0.f, 0.f};

    const unsigned short* Ar = Abf + (long)(bm + srow) * 320;
    const unsigned short* Br = Bbf + (long)(bn + srow) * 320;

    for (int k0 = 0; k0 < 320; k0 += 32) {
#pragma unroll
        for (int j = 0; j < 2; ++j) {
            int off = half * 16 + j * 8;
            *(uint4*)&As[srow * 40 + off] = *(const uint4*)(Ar + k0 + off);
            *(uint4*)&Bs[srow * 40 + off] = *(const uint4*)(Br + k0 + off);
        }
        __syncthreads();
        short8 af[2], bfv[8];
#pragma unroll
        for (int mi = 0; mi < 2; ++mi)
            af[mi] = *(const short8*)&As[(wave * 32 + mi * 16 + r16) * 40 + kh * 8];
#pragma unroll
        for (int ni = 0; ni < 8; ++ni)
            bfv[ni] = *(const short8*)&Bs[(ni * 16 + r16) * 40 + kh * 8];
#pragma unroll
        for (int mi = 0; mi < 2; ++mi)
#pragma unroll
            for (int ni = 0; ni < 8; ++ni)
                acc[mi][ni] = __builtin_amdgcn_mfma_f32_16x16x32_bf16(af[mi], bfv[ni], acc[mi][ni], 0, 0, 0);
        __syncthreads();
    }
#pragma unroll
    for (int ni = 0; ni < 8; ++ni) {
        int g = bn + ni * 16 + r16;
        if (g < NG_) {
            float bias = biasC[g];
#pragma unroll
            for (int mi = 0; mi < 2; ++mi) {
#pragma unroll
                for (int r = 0; r < 4; ++r) {
                    int row = bm + wave * 32 + mi * 16 + kh * 4 + r;
                    xg[(long)row * NG_ + g] = f32_to_bf16(acc[mi][ni][r] + bias);
                }
            }
        }
    }
}

// ---------------- LSTM recurrence: int8 weights in REGISTERS (the R3-R9 goal, finally
// capacity-feasible): 512 thr (cap 128, proven R3/R6), 400 active, 2 rows/thread
// = 2x(12 uint4 + uint2) = 100 VGPR + ~22 working <= 128. Zero weight LDS traffic/step:
// 13 h-broadcast reads + 100 v_dot4 + activations. LDS = h(208B) + gates(3.2KB) only.
// Rows: t<200 -> (i[t], g[t]); 200<=t<400 -> (f[t-200], o[t-200]).
__global__ __launch_bounds__(512) void lstm_rec(const unsigned short* __restrict__ xg,
                                                const signed char* __restrict__ w8,
                                                const float* __restrict__ invs,
                                                float* __restrict__ lstm_out) {
    __shared__ __align__(16) unsigned char hbuf[208];   // int8 h (200 used, 8 pad)
    __shared__ float a_lds[800];                        // gate activations [q*200+ko]
    int tid = threadIdx.x;
    int dir = blockIdx.x >> 6;
    int b = blockIdx.x & 63;
    bool act = tid < 400;
    int tw = act ? tid : 0;

    const unsigned char* wbase = (const unsigned char*)w8 + dir * 160000;
    uint4 wA[12], wB[12];
    uint2 wAt, wBt;
#pragma unroll
    for (int j = 0; j < 12; ++j) {
        wA[j] = *(const uint4*)(wbase + (size_t)(j * 800 + tw) * 16);
        wB[j] = *(const uint4*)(wbase + (size_t)(j * 800 + tw + 400) * 16);
    }
    wAt = *(const uint2*)(wbase + 153600 + (size_t)tw * 8);
    wBt = *(const uint2*)(wbase + 153600 + (size_t)(tw + 400) * 8);
    // Pin against rematerialization (R4/R5 lesson).
#pragma unroll
    for (int j = 0; j < 12; ++j) {
        asm volatile("" : "+v"(wA[j].x), "+v"(wA[j].y), "+v"(wA[j].z), "+v"(wA[j].w));
        asm volatile("" : "+v"(wB[j].x), "+v"(wB[j].y), "+v"(wB[j].z), "+v"(wB[j].w));
    }
    asm volatile("" : "+v"(wAt.x), "+v"(wAt.y), "+v"(wBt.x), "+v"(wBt.y));

    float invA = act ? invs[dir * 800 + tid] : 0.f;
    float invB = act ? invs[dir * 800 + tid + 400] : 0.f;
    if (tid < 52) ((unsigned*)hbuf)[tid] = 0u;   // h=0 (incl. pad)
    float c = 0.f;
    __syncthreads();

    const uint4* h4c = (const uint4*)hbuf;
    const uint2* ht2 = (const uint2*)(hbuf + 192);
    const unsigned short* xbase = xg + (long)b * L_ * NG_ + dir * 800;

    int t0 = dir ? (L_ - 1) : 0;
    float xa = act ? bf16_to_f32(xbase[(long)t0 * NG_ + tid]) : 0.f;
    float xb = act ? bf16_to_f32(xbase[(long)t0 * NG_ + tid + 400]) : 0.f;

    for (int step = 0; step < L_; ++step) {
        int t = dir ? (L_ - 1 - step) : step;
        float xa_n = 0.f, xb_n = 0.f;
        if (act && step + 1 < L_) {
            int tn = dir ? (t - 1) : (t + 1);
            xa_n = bf16_to_f32(xbase[(long)tn * NG_ + tid]);
            xb_n = bf16_to_f32(xbase[(long)tn * NG_ + tid + 400]);
        }
        if (act) {
            int di0 = 0, di1 = 0;
#pragma unroll
            for (int j = 0; j < 12; ++j) {
                uint4 hh = h4c[j];
                di0 = dot4(wA[j].x, hh.x, di0); di0 = dot4(wA[j].y, hh.y, di0);
                di0 = dot4(wA[j].z, hh.z, di0); di0 = dot4(wA[j].w, hh.w, di0);
                di1 = dot4(wB[j].x, hh.x, di1); di1 = dot4(wB[j].y, hh.y, di1);
                di1 = dot4(wB[j].z, hh.z, di1); di1 = dot4(wB[j].w, hh.w, di1);
            }
            {
                uint2 hh = ht2[0];
                di0 = dot4(wAt.x, hh.x, di0); di0 = dot4(wAt.y, hh.y, di0);
                di1 = dot4(wBt.x, hh.x, di1); di1 = dot4(wBt.y, hh.y, di1);
            }
            float pa = xa + (float)di0 * invA;   // i (t<200) / f
            float pb = xb + (float)di1 * invB;   // g (t<200) / o
            a_lds[tid] = 1.f / (1.f + __expf(-pa));
            if (tid < 200) {
                float e = __expf(-2.f * pb);                     // tanh(g)
                a_lds[400 + tid] = 2.f / (1.f + e) - 1.f;
            } else {
                a_lds[400 + tid] = 1.f / (1.f + __expf(-pb));    // sig(o)
            }
        }
        __syncthreads();
        if (tid < HD_) {
            float ig = a_lds[tid];
            float fg = a_lds[200 + tid];
            float gg = a_lds[400 + tid];
            float og = a_lds[600 + tid];
            c = fg * c + ig * gg;
            float ec = __expf(-2.f * c);
            float hn = og * (2.f / (1.f + ec) - 1.f);
            ((signed char*)hbuf)[tid] = (signed char)(int)rintf(hn * 127.f);
            lstm_out[((long)(b * L_ + t)) * H_ + dir * HD_ + tid] = hn;
        }
        xa = xa_n; xb = xb_n;
        __syncthreads();
    }
}

// ---------------- features = lstm_out @ W_tag^T + b_tag (unchanged)
__global__ __launch_bounds__(256) void feat_kernel(const float* __restrict__ lstm_out,
                                                   const float* __restrict__ wtagT,
                                                   const float* __restrict__ btag,
                                                   float* __restrict__ feats) {
    __shared__ float hrow[4 * H_];
    int tid = threadIdx.x;
    int base = blockIdx.x * 4;
    for (int idx = tid; idx < 4 * H_; idx += 256)
        hrow[idx] = lstm_out[(long)base * H_ + idx];
    __syncthreads();
    int il = tid >> 6, s = tid & 63;
    if (s < S_) {
        float acc = btag[s];
        const float* hr = hrow + il * H_;
#pragma unroll 4
        for (int k = 0; k < H_; ++k)
            acc = fmaf(hr[k], wtagT[k * S_ + s], acc);
        feats[(base + il) * S_ + s] = acc;
    }
}

// ---------------- CRF forward + labeled score (per-batch partials, no atomics)
__global__ __launch_bounds__(512) void crf_kernel(const float* __restrict__ feats,
                                                  const float* __restrict__ trans,
                                                  const int* __restrict__ tags,
                                                  const int* __restrict__ seqlens,
                                                  float* __restrict__ part) {
    __shared__ float Tt[S_ * S_];   // Tt[j*50+i] = trans[i*50+j]
    __shared__ float alpha[S_];
    __shared__ float lastal[S_];
    __shared__ int tg[L_];
    int tid = threadIdx.x;
    int b = blockIdx.x;
    for (int idx = tid; idx < S_ * S_; idx += 512) {
        int j = idx / S_, i = idx % S_;
        Tt[idx] = trans[i * S_ + j];
    }
    if (tid < L_) tg[tid] = tags[b * L_ + tid];
    int slen = seqlens[b];
    const float* fb = feats + (long)b * L_ * S_;
    __syncthreads();
    if (tid < S_) {
        float a = Tt[tid * S_ + START_] + fb[tid];
        alpha[tid] = a;
        if (slen == 1) lastal[tid] = a;
    }
    __syncthreads();
    int j = tid >> 3, sub = tid & 7;
    bool jact = j < S_;
    for (int t = 1; t < L_; ++t) {
        float anew = 0.f;
        if (jact) {
            float m = -1e30f;
            for (int i = sub; i < S_; i += 8) m = fmaxf(m, alpha[i] + Tt[j * S_ + i]);
            m = fmaxf(m, __shfl_xor(m, 1));
            m = fmaxf(m, __shfl_xor(m, 2));
            m = fmaxf(m, __shfl_xor(m, 4));
            float s = 0.f;
            for (int i = sub; i < S_; i += 8) s += __expf(alpha[i] + Tt[j * S_ + i] - m);
            s += __shfl_xor(s, 1);
            s += __shfl_xor(s, 2);
            s += __shfl_xor(s, 4);
            anew = m + __logf(s) + fb[t * S_ + j];
        }
        __syncthreads();
        if (jact && sub == 0) {
            alpha[j] = anew;
            if (t == slen - 1) lastal[j] = anew;
        }
        __syncthreads();
    }
    if (tid < 64) {
        float la = (tid < S_) ? (lastal[tid] + Tt[END_ * S_ + tid]) : -1e30f;
        float m = la;
        for (int off = 32; off; off >>= 1) m = fmaxf(m, __shfl_xor(m, off));
        float e = (tid < S_) ? __expf(la - m) : 0.f;
        for (int off = 32; off; off >>= 1) e += __shfl_xor(e, off);
        float unl = m + __logf(e);
        float lab = 0.f;
        for (int tt = tid; tt < L_; tt += 64) {
            if (tt == 0) {
                lab += Tt[tg[0] * S_ + START_] + fb[tg[0]];
            } else if (tt < slen) {
                lab += Tt[tg[tt] * S_ + tg[tt - 1]] + fb[tt * S_ + tg[tt]];
            }
        }
        if (tid == 0) lab += Tt[END_ * S_ + tg[slen - 1]];
        for (int off = 32; off; off >>= 1) lab += __shfl_xor(lab, off);
        if (tid == 0) part[b] = unl - lab;
    }
}

// ---------------- final: deterministic fixed-order sum of 64 partials
__global__ void fin_kernel(const float* __restrict__ part, float* __restrict__ out) {
    float s = 0.f;
    for (int i = 0; i < B_; ++i) s += part[i];
    out[0] = s;
}

extern "C" void kernel_launch(void* const* d_in, const int* in_sizes, int n_in,
                              void* d_out, int out_size, void* d_ws, size_t ws_size,
                              hipStream_t stream) {
    const int*   words = (const int*)d_in[0];
    const int*   slens = (const int*)d_in[1];
    // d_in[2] = masks: semantically (t < seq_len); not read.
    const int*   tags  = (const int*)d_in[3];
    const float* emb   = (const float*)d_in[4];
    const float* wihf  = (const float*)d_in[5];
    const float* whhf  = (const float*)d_in[6];
    const float* bf    = (const float*)d_in[7];
    const float* wihb  = (const float*)d_in[8];
    const float* whhb  = (const float*)d_in[9];
    const float* bb    = (const float*)d_in[10];
    const float* wtag  = (const float*)d_in[11];
    const float* btag  = (const float*)d_in[12];
    const float* trans = (const float*)d_in[13];

    char* ws = (char*)d_ws;
    unsigned short* xg   = (unsigned short*)(ws + OFF_XG);
    float*          lstm = (float*)(ws + OFF_LSTM);
    unsigned short* Abf  = (unsigned short*)(ws + OFF_ABF);  // prep -> xg (overlays lstm)
    unsigned short* Bbf  = (unsigned short*)(ws + OFF_BBF);  // prep -> xg (overlays lstm)
    signed char*    w8   = (signed char*)(ws + OFF_SH);      // quant -> lstm
    float*          fts  = (float*)(ws + OFF_SH);            // feat -> crf (time-shared)
    float*          invs = (float*)(ws + OFF_INV);
    float*          wtT  = (float*)(ws + OFF_WTT);
    float*          biaC = (float*)(ws + OFF_BIA);
    float*          part = (float*)(ws + OFF_PART);
    float*          out  = (float*)d_out;

    prep_kernel<<<PREP_BLOCKS, 256, 0, stream>>>(words, emb, wihf, wihb, bf, bb,
                                                 wtag, Abf, Bbf, wtT, biaC);
    quant_kernel<<<400, 256, 0, stream>>>(whhf, whhb, w8, invs);
    xg_gemm<<<dim3(13, 64), 256, 0, stream>>>(Abf, Bbf, biaC, xg);
    lstm_rec<<<128, 512, 0, stream>>>(xg, w8, invs, lstm);
    feat_kernel<<<2048, 256, 0, stream>>>(lstm, wtT, btag, fts);
    crf_kernel<<<64, 512, 0, stream>>>(fts, trans, tags, slens, part);
    fin_kernel<<<1, 1, 0, stream>>>(part, out);
}